// Round 3
// baseline (457.216 us; speedup 1.0000x reference)
//
#include <hip/hip_runtime.h>
#include <hip/hip_bf16.h>
#include <stdint.h>

typedef __bf16 bf16_t;
typedef bf16_t bf16x8 __attribute__((ext_vector_type(8)));
typedef float f32x4 __attribute__((ext_vector_type(4)));

#define BATCH 16
#define HH    56
#define DIMK  384
#define M_TOT (BATCH*HH*HH)   // 50176

// ---------------------------------------------------------------------------
// Fallback: zero d_out (diagnostic if ws_size too small -> absmax = 2.171875)
__global__ void k_zero(float* __restrict__ p, int n) {
  int i = blockIdx.x * 256 + threadIdx.x;
  if (i < n) p[i] = 0.f;
}

// Prep 1: transpose w_qkv [384][1152] fp32 -> wT [1152][384] bf16
__global__ void k_transpose(const float* __restrict__ w, bf16_t* __restrict__ wT) {
  int idx = blockIdx.x * 256 + threadIdx.x;
  if (idx >= 1152 * 384) return;
  int n = idx / 384, k = idx - n * 384;
  wT[idx] = (bf16_t)w[k * 1152 + n];
}

// Prep 2: wcombT[n][k] = sum_j w_out[k][j] * w_post[j][n]  (fp32 in, bf16 out)
//         bcomb[n]     = sum_j b_out[j] * w_post[j][n] + b_post[n]  (fp32)
__global__ void k_comb(const float* __restrict__ w_out, const float* __restrict__ b_out,
                       const float* __restrict__ w_post, const float* __restrict__ b_post,
                       bf16_t* __restrict__ wcombT, float* __restrict__ bcomb) {
  __shared__ float col[384];
  const int n = blockIdx.x, t = threadIdx.x;
  for (int j = t; j < 384; j += 256) col[j] = w_post[j * 384 + n];
  __syncthreads();
  for (int k = t; k < 384; k += 256) {
    float acc = 0.f;
    for (int j = 0; j < 384; ++j) acc += w_out[k * 384 + j] * col[j];
    wcombT[n * 384 + k] = (bf16_t)acc;
  }
  if (t == 0) {
    float acc = b_post[n];
    for (int j = 0; j < 384; ++j) acc += b_out[j] * col[j];
    bcomb[n] = acc;
  }
}

// ---------------------------------------------------------------------------
// GEMM, 128x128 tile, BK=32, bf16 MFMA 16x16x32, fp32 accumulate.
// MODE 0: A = x fp32 [M][384], rows gathered with roll(-3,-3), cvt->bf16 in
//         staging; C = qkv bf16 [M][1152].
// MODE 1: A = qkv bf16 [M][lda=1152] (q slot, attn output); C = out fp32
//         [M][384], rows scattered with roll(+3,+3), + bias.
template<int MODE>
__global__ __launch_bounds__(256)
void k_gemm(const void* __restrict__ Av, const bf16_t* __restrict__ B,
            void* __restrict__ Cv, const float* __restrict__ bias,
            int Ndim, int Kdim, int lda) {
  __shared__ __align__(16) bf16_t As[128 * 32];
  __shared__ __align__(16) bf16_t Bs[128 * 32];
  const int tid  = threadIdx.x;
  const int wave = tid >> 6;
  const int lane = tid & 63;
  const int wr = wave >> 1, wc = wave & 1;
  const int row0 = blockIdx.y * 128;
  const int col0 = blockIdx.x * 128;

  const float*  afp[2];   // MODE 0
  const bf16_t* abf[2];   // MODE 1
  const bf16_t* bptr[2];
  int lin[2];
#pragma unroll
  for (int c = 0; c < 2; ++c) {
    int linear = c * 256 + tid;
    lin[c] = linear;
    int r  = linear >> 2;       // tile row (0..127)
    int kc = linear & 3;        // 16-element... 8-element K chunk index
    int grow = row0 + r;
    int srow;
    if (MODE == 0) {
      int bb  = grow / 3136;
      int rem = grow - bb * 3136;
      int i = rem / 56;
      int j = rem - i * 56;
      int si = i + 3; if (si >= 56) si -= 56;
      int sj = j + 3; if (sj >= 56) sj -= 56;
      srow = bb * 3136 + si * 56 + sj;     // fused roll(-3,-3) on input read
      afp[c] = (const float*)Av + (size_t)srow * lda + kc * 8;
    } else {
      srow = grow;
      abf[c] = (const bf16_t*)Av + (size_t)srow * lda + kc * 8;
    }
    bptr[c] = B + (size_t)(col0 + r) * Kdim + kc * 8;
  }

  f32x4 acc[4][4] = {};
  const int lr = lane >> 4;   // quad
  const int lc = lane & 15;
  unsigned aoff[4], boff[4];
#pragma unroll
  for (int mi = 0; mi < 4; ++mi) aoff[mi] = (unsigned)((wr * 64 + mi * 16 + lc) * 32 + lr * 8);
#pragma unroll
  for (int ni = 0; ni < 4; ++ni) boff[ni] = (unsigned)((wc * 64 + ni * 16 + lc) * 32 + lr * 8);

  const int kiters = Kdim >> 5;
  for (int kt = 0; kt < kiters; ++kt) {
    const int koff = kt * 32;
    bf16x8 va[2], vb[2];
#pragma unroll
    for (int c = 0; c < 2; ++c) {
      if (MODE == 0) {
        f32x4 lo = *(const f32x4*)(afp[c] + koff);
        f32x4 hi = *(const f32x4*)(afp[c] + koff + 4);
#pragma unroll
        for (int u = 0; u < 4; ++u) { va[c][u] = (bf16_t)lo[u]; va[c][u + 4] = (bf16_t)hi[u]; }
      } else {
        va[c] = *(const bf16x8*)(abf[c] + koff);
      }
      vb[c] = *(const bf16x8*)(bptr[c] + koff);
    }
    __syncthreads();            // previous iteration's LDS reads complete
#pragma unroll
    for (int c = 0; c < 2; ++c) {
      *(bf16x8*)(As + lin[c] * 8) = va[c];
      *(bf16x8*)(Bs + lin[c] * 8) = vb[c];
    }
    __syncthreads();
    bf16x8 af[4], bfr[4];
#pragma unroll
    for (int mi = 0; mi < 4; ++mi) af[mi]  = *(const bf16x8*)(As + aoff[mi]);
#pragma unroll
    for (int ni = 0; ni < 4; ++ni) bfr[ni] = *(const bf16x8*)(Bs + boff[ni]);
#pragma unroll
    for (int mi = 0; mi < 4; ++mi)
#pragma unroll
      for (int ni = 0; ni < 4; ++ni)
        acc[mi][ni] = __builtin_amdgcn_mfma_f32_16x16x32_bf16(af[mi], bfr[ni], acc[mi][ni], 0, 0, 0);
  }

  // Epilogue: C/D layout col=lane&15, row=quad*4+reg (verified m89/m91)
#pragma unroll
  for (int mi = 0; mi < 4; ++mi) {
#pragma unroll
    for (int rr = 0; rr < 4; ++rr) {
      int grow = row0 + wr * 64 + mi * 16 + lr * 4 + rr;
      size_t orow;
      if (MODE == 1) {
        int bb  = grow / 3136;
        int rem = grow - bb * 3136;
        int i = rem / 56;
        int j = rem - i * 56;
        int si = i + 3; if (si >= 56) si -= 56;
        int sj = j + 3; if (sj >= 56) sj -= 56;
        orow = (size_t)(bb * 3136 + si * 56 + sj);   // fused roll(+3,+3) on write
      } else {
        orow = (size_t)grow;
      }
#pragma unroll
      for (int ni = 0; ni < 4; ++ni) {
        int gcol = col0 + wc * 64 + ni * 16 + lc;
        float v = acc[mi][ni][rr];
        if (MODE == 1) {
          ((float*)Cv)[orow * (size_t)Ndim + gcol] = v + bias[gcol];
        } else {
          ((bf16_t*)Cv)[orow * (size_t)Ndim + gcol] = (bf16_t)v;
        }
      }
    }
  }
}

// ---------------------------------------------------------------------------
// Attention: one wave per (batch, head, window). 49 tokens, head_dim 32.
// qkv layout: [m][1152] bf16, col = sel*384 + head*32 + d (shifted coords).
// Output written IN PLACE into the q slot (head-disjoint columns; q reads
// precede writes in program order within the sole owning block).
__global__ __launch_bounds__(64)
void k_attn(const float* __restrict__ pos, bf16_t* __restrict__ qkv) {
  __shared__ float ks[49][32];
  __shared__ float vs[49][32];
  __shared__ float ps[169];
  __shared__ float pd[49][49];
  const int w = blockIdx.x, head = blockIdx.y, b = blockIdx.z;
  const int wy = w >> 3, wx = w & 7;
  const int lane = threadIdx.x;
  for (int t = lane; t < 169; t += 64) ps[t] = pos[t];

  float q[32];
  size_t m = 0;
  int ty = 0, tx = 0;
  if (lane < 49) {
    ty = lane / 7; tx = lane - ty * 7;
    const int i = wy * 7 + ty, j = wx * 7 + tx;
    m = (size_t)(b * 3136 + i * 56 + j);
    const bf16_t* base = qkv + m * 1152 + head * 32;
#pragma unroll
    for (int c = 0; c < 4; ++c) {
      bf16x8 tq = *(const bf16x8*)(base + c * 8);
      bf16x8 tk = *(const bf16x8*)(base + 384 + c * 8);
      bf16x8 tv = *(const bf16x8*)(base + 768 + c * 8);
#pragma unroll
      for (int u = 0; u < 8; ++u) {
        q[c * 8 + u] = (float)tq[u];
        ks[lane][c * 8 + u] = (float)tk[u];
        vs[lane][c * 8 + u] = (float)tv[u];
      }
    }
  }
  __syncthreads();
  if (lane >= 49) return;

  const bool mU = (wy == 7), mL = (wx == 7);
  float mx = -1e30f;
  for (int j = 0; j < 49; ++j) {
    float s = 0.f;
#pragma unroll
    for (int d = 0; d < 32; ++d) s += q[d] * ks[j][d];
    const int jy = j / 7, jx = j - jy * 7;
    s = s * 0.17677669529663687f + ps[(jy - ty + 6) * 13 + (jx - tx + 6)];
    const bool dead = (mU && ((lane >= 28) != (j >= 28))) ||
                      (mL && ((tx >= 4) != (jx >= 4)));
    s = dead ? -1e30f : s;
    pd[lane][j] = s;
    mx = fmaxf(mx, s);
  }
  float l = 0.f;
  for (int j = 0; j < 49; ++j) {
    float p = __expf(pd[lane][j] - mx);
    pd[lane][j] = p;
    l += p;
  }
  const float rl = 1.f / l;
  float o[32];
#pragma unroll
  for (int d = 0; d < 32; ++d) o[d] = 0.f;
  for (int j = 0; j < 49; ++j) {
    const float p = pd[lane][j];
#pragma unroll
    for (int d = 0; d < 32; ++d) o[d] += p * vs[j][d];
  }
  bf16_t* ob = qkv + m * 1152 + head * 32;   // in-place into q slot
#pragma unroll
  for (int c = 0; c < 4; ++c) {
    bf16x8 t;
#pragma unroll
    for (int u = 0; u < 8; ++u) t[u] = (bf16_t)(o[c * 8 + u] * rl);
    *(bf16x8*)(ob + c * 8) = t;
  }
}

// ---------------------------------------------------------------------------
extern "C" void kernel_launch(void* const* d_in, const int* in_sizes, int n_in,
                              void* d_out, int out_size, void* d_ws, size_t ws_size,
                              hipStream_t stream) {
  // Reference dtypes: ALL inputs float32; output float32.
  const float* x      = (const float*)d_in[0];
  const float* w_qkv  = (const float*)d_in[1];
  const float* pos    = (const float*)d_in[2];
  const float* w_out  = (const float*)d_in[3];
  const float* b_out  = (const float*)d_in[4];
  const float* w_post = (const float*)d_in[5];
  const float* b_post = (const float*)d_in[6];
  float* out = (float*)d_out;

  const size_t SZ_QKV = (size_t)M_TOT * 1152 * 2;   // 115.6 MB (bf16 intermediate)
  const size_t SZ_WT  = (size_t)1152 * 384 * 2;
  const size_t SZ_WC  = (size_t)384 * 384 * 2;
  const size_t SZ_BC  = 384 * 4;
  const size_t NEEDED = SZ_QKV + SZ_WT + SZ_WC + SZ_BC;

  if (ws_size < NEEDED) {
    k_zero<<<(out_size + 255) / 256, 256, 0, stream>>>(out, out_size);
    return;
  }

  char* ws = (char*)d_ws;
  bf16_t* qkv = (bf16_t*)ws;
  bf16_t* wT  = (bf16_t*)(ws + SZ_QKV);
  bf16_t* wcT = (bf16_t*)(ws + SZ_QKV + SZ_WT);
  float*  bc  = (float*)(ws + SZ_QKV + SZ_WT + SZ_WC);

  k_transpose<<<1728, 256, 0, stream>>>(w_qkv, wT);
  k_comb<<<384, 256, 0, stream>>>(w_out, b_out, w_post, b_post, wcT, bc);
  // qkv = roll(x) @ w_qkv   [50176 x 1152], bf16
  k_gemm<0><<<dim3(9, 392), 256, 0, stream>>>(x, wT, qkv, nullptr, 1152, DIMK, DIMK);
  // attention, in-place into q slot of qkv (row stride 1152)
  k_attn<<<dim3(64, 12, 16), 64, 0, stream>>>(pos, qkv);
  // out = roll^{-1}( attn_out @ (w_out@w_post) + bcomb )   [50176 x 384], fp32
  k_gemm<1><<<dim3(3, 392), 256, 0, stream>>>(qkv, wcT, out, bc, 384, DIMK, 1152);
}

// Round 4
// 341.427 us; speedup vs baseline: 1.3391x; 1.3391x over previous
//
#include <hip/hip_runtime.h>
#include <hip/hip_bf16.h>
#include <stdint.h>

typedef __bf16 bf16_t;
typedef bf16_t bf16x8 __attribute__((ext_vector_type(8)));
typedef bf16_t bf16x4 __attribute__((ext_vector_type(4)));
typedef float f32x4 __attribute__((ext_vector_type(4)));

#define BATCH 16
#define HH    56
#define DIMK  384
#define M_TOT (BATCH*HH*HH)   // 50176
#define SCALE 0.17677669529663687f

__device__ __forceinline__ void async_load16(const bf16_t* g, const bf16_t* l) {
  __builtin_amdgcn_global_load_lds((const __attribute__((address_space(1))) void*)g,
                                   (__attribute__((address_space(3))) void*)l,
                                   16, 0, 0);
}

// DPP rotate within 16-lane row (VALU pipe — keeps softmax off the LDS pipe)
template<int CTRL>
__device__ __forceinline__ float dpp_ror(float x) {
  return __int_as_float(__builtin_amdgcn_mov_dpp(__float_as_int(x), CTRL, 0xf, 0xf, false));
}
__device__ __forceinline__ float rowmax16(float v) {
  v = fmaxf(v, dpp_ror<0x121>(v));  // row_ror:1
  v = fmaxf(v, dpp_ror<0x122>(v));  // row_ror:2
  v = fmaxf(v, dpp_ror<0x124>(v));  // row_ror:4
  v = fmaxf(v, dpp_ror<0x128>(v));  // row_ror:8
  return v;
}
__device__ __forceinline__ float rowsum16(float v) {
  v += dpp_ror<0x121>(v);
  v += dpp_ror<0x122>(v);
  v += dpp_ror<0x124>(v);
  v += dpp_ror<0x128>(v);
  return v;
}

// ---------------------------------------------------------------------------
__global__ void k_zero(float* __restrict__ p, int n) {
  int i = blockIdx.x * 256 + threadIdx.x;
  if (i < n) p[i] = 0.f;
}

// transpose w_qkv [384][1152] fp32 -> wT [1152][384] bf16
__global__ void k_transpose(const float* __restrict__ w, bf16_t* __restrict__ wT) {
  int idx = blockIdx.x * 256 + threadIdx.x;
  if (idx >= 1152 * 384) return;
  int n = idx / 384, k = idx - n * 384;
  wT[idx] = (bf16_t)w[k * 1152 + n];
}

// wcombT[n][k] = sum_j w_out[k][j] * w_post[j][n]; bcomb[n] = b_out@w_post + b_post
__global__ void k_comb(const float* __restrict__ w_out, const float* __restrict__ b_out,
                       const float* __restrict__ w_post, const float* __restrict__ b_post,
                       bf16_t* __restrict__ wcombT, float* __restrict__ bcomb) {
  __shared__ float col[384];
  const int n = blockIdx.x, t = threadIdx.x;
  for (int j = t; j < 384; j += 256) col[j] = w_post[j * 384 + n];
  __syncthreads();
  for (int k = t; k < 384; k += 256) {
    float acc = 0.f;
    for (int j = 0; j < 384; ++j) acc += w_out[k * 384 + j] * col[j];
    wcombT[n * 384 + k] = (bf16_t)acc;
  }
  if (t == 0) {
    float acc = b_post[n];
    for (int j = 0; j < 384; ++j) acc += b_out[j] * col[j];
    bcomb[n] = acc;
  }
}

// bias/mask init table in MFMA C-layout, pre-divided by SCALE.
// layout: [cls 0..3][tile=mt*4+nt][lane][reg] fp32  (64 KB)
__global__ void k_bias(const float* __restrict__ pos, float* __restrict__ biasC) {
  int idx = blockIdx.x * 256 + threadIdx.x;
  if (idx >= 4 * 16 * 64 * 4) return;
  int reg = idx & 3, lane = (idx >> 2) & 63, tile = (idx >> 8) & 15, cls = idx >> 12;
  int mt = tile >> 2, nt = tile & 3, lc = lane & 15, quad = lane >> 4;
  int m = mt * 16 + quad * 4 + reg, n = nt * 16 + lc;
  float v = -1e32f;
  if (m < 49 && n < 49) {
    int ty = m / 7, tx = m % 7, jy = n / 7, jx = n % 7;
    bool dead = ((cls & 1) && ((m >= 28) != (n >= 28))) ||
                ((cls & 2) && ((tx >= 4) != (jx >= 4)));
    v = dead ? -1e32f : pos[(jy - ty + 6) * 13 + (jx - tx + 6)] * (1.0f / SCALE);
  }
  biasC[idx] = v;
}

// x fp32 -> bf16 with roll(-3,-3) fused.  xb lives in d_out (dead scratch).
__global__ void k_convroll(const float* __restrict__ x, bf16_t* __restrict__ xb) {
  int idx = blockIdx.x * 256 + threadIdx.x;
  if (idx >= M_TOT * 96) return;
  int row = idx / 96, c = idx - row * 96;
  int bb = row / 3136, rem = row - bb * 3136, i = rem / 56, j = rem - i * 56;
  int si = i + 3; if (si >= 56) si -= 56;
  int sj = j + 3; if (sj >= 56) sj -= 56;
  f32x4 v = *(const f32x4*)(x + ((size_t)(bb * 3136 + si * 56 + sj)) * 384 + c * 4);
  bf16x4 o;
#pragma unroll
  for (int u = 0; u < 4; ++u) o[u] = (bf16_t)v[u];
  *(bf16x4*)(xb + (size_t)row * 384 + c * 4) = o;
}

// ---------------------------------------------------------------------------
// GEMM: C[M x N] = A[M x K(lda)] * B^T[N x K], 128x128 tile, BK=32,
// async global->LDS staging (m97 width-16). MODE 1: fp32 C + roll(+3,+3) + bias.
template<int MODE>
__global__ __launch_bounds__(256)
void k_gemm(const bf16_t* __restrict__ A, const bf16_t* __restrict__ B,
            void* __restrict__ Cv, const float* __restrict__ bias,
            int Ndim, int Kdim, int lda) {
  __shared__ __align__(16) bf16_t As[128 * 32];
  __shared__ __align__(16) bf16_t Bs[128 * 32];
  const int tid  = threadIdx.x;
  const int wave = tid >> 6;
  const int lane = tid & 63;
  const int wr = wave >> 1, wc = wave & 1;
  const int row0 = blockIdx.y * 128;
  const int col0 = blockIdx.x * 128;

  const bf16_t* aptr[2];
  const bf16_t* bptr[2];
  int lin[2];
#pragma unroll
  for (int c = 0; c < 2; ++c) {
    int linear = c * 256 + tid;
    lin[c] = linear;
    int r  = linear >> 2;
    int kc = linear & 3;
    aptr[c] = A + (size_t)(row0 + r) * lda + kc * 8;
    bptr[c] = B + (size_t)(col0 + r) * Kdim + kc * 8;
  }

  f32x4 acc[4][4] = {};
  const int lr = lane >> 4;
  const int lc = lane & 15;
  unsigned aoff[4], boff[4];
#pragma unroll
  for (int mi = 0; mi < 4; ++mi) aoff[mi] = (unsigned)((wr * 64 + mi * 16 + lc) * 32 + lr * 8);
#pragma unroll
  for (int ni = 0; ni < 4; ++ni) boff[ni] = (unsigned)((wc * 64 + ni * 16 + lc) * 32 + lr * 8);

  const int kiters = Kdim >> 5;
  for (int kt = 0; kt < kiters; ++kt) {
    const int koff = kt * 32;
    async_load16(aptr[0] + koff, As + lin[0] * 8);
    async_load16(aptr[1] + koff, As + lin[1] * 8);
    async_load16(bptr[0] + koff, Bs + lin[0] * 8);
    async_load16(bptr[1] + koff, Bs + lin[1] * 8);
    __syncthreads();   // vmcnt(0) drained before barrier (m97 semantics)
    bf16x8 af[4], bfr[4];
#pragma unroll
    for (int mi = 0; mi < 4; ++mi) af[mi]  = *(const bf16x8*)(As + aoff[mi]);
#pragma unroll
    for (int ni = 0; ni < 4; ++ni) bfr[ni] = *(const bf16x8*)(Bs + boff[ni]);
#pragma unroll
    for (int mi = 0; mi < 4; ++mi)
#pragma unroll
      for (int ni = 0; ni < 4; ++ni)
        acc[mi][ni] = __builtin_amdgcn_mfma_f32_16x16x32_bf16(af[mi], bfr[ni], acc[mi][ni], 0, 0, 0);
    __syncthreads();   // all frags consumed before next iter's async stores
  }

  // Epilogue: C/D layout col=lane&15, row=quad*4+reg (verified m89/m91)
#pragma unroll
  for (int mi = 0; mi < 4; ++mi) {
#pragma unroll
    for (int rr = 0; rr < 4; ++rr) {
      int grow = row0 + wr * 64 + mi * 16 + lr * 4 + rr;
      size_t orow;
      if (MODE == 1) {
        int bb  = grow / 3136;
        int rem = grow - bb * 3136;
        int i = rem / 56;
        int j = rem - i * 56;
        int si = i + 3; if (si >= 56) si -= 56;
        int sj = j + 3; if (sj >= 56) sj -= 56;
        orow = (size_t)(bb * 3136 + si * 56 + sj);   // fused roll(+3,+3)
      } else {
        orow = (size_t)grow;
      }
#pragma unroll
      for (int ni = 0; ni < 4; ++ni) {
        int gcol = col0 + wc * 64 + ni * 16 + lc;
        float v = acc[mi][ni][rr];
        if (MODE == 1) {
          ((float*)Cv)[orow * (size_t)Ndim + gcol] = v + bias[gcol];
        } else {
          ((bf16_t*)Cv)[orow * (size_t)Ndim + gcol] = (bf16_t)v;
        }
      }
    }
  }
}

// ---------------------------------------------------------------------------
// MFMA attention: one wave per (b, head, window); 4 waves/block.
// 49 tokens padded to 64. Q/K/V fragments loaded directly from global
// (per-lane row addresses, clamp row 48 for pads). Bias+mask pre-baked in
// C-layout (biasC). Softmax reduce via DPP row_ror. P via LDS (stride 72).
// Output written in place into the q slot of qkv.
__global__ __launch_bounds__(256)
void k_attn(const float* __restrict__ biasC, bf16_t* __restrict__ qkv) {
  __shared__ __align__(16) bf16_t Ps[4 * 64 * 72];   // 36864 B
  const int tid = threadIdx.x, wid = tid >> 6, lane = tid & 63;
  const int p = blockIdx.x * 4 + wid;                 // 12288 problems
  const int b = p / 768, rem = p - b * 768;
  const int head = rem >> 6, w = rem & 63;
  const int wy = w >> 3, wx = w & 7;
  const int cls = ((wy == 7) ? 1 : 0) | ((wx == 7) ? 2 : 0);
  const int lc = lane & 15, quad = lane >> 4;
  const size_t wbase = ((size_t)b * 3136 + (size_t)wy * 7 * 56 + (size_t)wx * 7) * 1152
                       + head * 32;

  // row offset (elements) for token m within this window
  auto rowoff = [&](int m) -> size_t {
    int ty = m / 7, tx = m - ty * 7;
    return wbase + (size_t)(ty * 56 + tx) * 1152;
  };

  // --- Q (A-frag) and K (B-frag) direct global loads; same rows serve both.
  bf16x8 qf[4], kf[4];
#pragma unroll
  for (int t = 0; t < 4; ++t) {
    int m = t * 16 + lc; if (m > 48) m = 48;
    const bf16_t* r = qkv + rowoff(m);
    qf[t] = *(const bf16x8*)(r + quad * 8);          // Q row m, k-chunk quad
    kf[t] = *(const bf16x8*)(r + 384 + quad * 8);    // K row m (as B-frag col)
  }

  // --- V B-frags: scalar global loads V[n=kc*32+quad*8+u][d=dt*16+lc]
  bf16x8 vf[2][2];
#pragma unroll
  for (int kc = 0; kc < 2; ++kc)
#pragma unroll
    for (int u = 0; u < 8; ++u) {
      int n = kc * 32 + quad * 8 + u; if (n > 48) n = 48;
      const bf16_t* r = qkv + rowoff(n) + 768 + lc;
      vf[kc][0][u] = r[0];
      vf[kc][1][u] = r[16];
    }

  // --- S = Q.K^T with acc initialized to (bias+mask)/SCALE
  f32x4 acc[4][4];
  const float* bp = biasC + cls * 4096 + lane * 4;
#pragma unroll
  for (int mt = 0; mt < 4; ++mt)
#pragma unroll
    for (int nt = 0; nt < 4; ++nt)
      acc[mt][nt] = *(const f32x4*)(bp + (mt * 4 + nt) * 256);
#pragma unroll
  for (int mt = 0; mt < 4; ++mt)
#pragma unroll
    for (int nt = 0; nt < 4; ++nt)
      acc[mt][nt] = __builtin_amdgcn_mfma_f32_16x16x32_bf16(qf[mt], kf[nt], acc[mt][nt], 0, 0, 0);

  // --- softmax over n (row m = mt*16+quad*4+reg; 16 cols/lane-row × 4 nt)
  float l[4][4];
#pragma unroll
  for (int mt = 0; mt < 4; ++mt)
#pragma unroll
    for (int reg = 0; reg < 4; ++reg) {
      float mx = fmaxf(fmaxf(acc[mt][0][reg], acc[mt][1][reg]),
                       fmaxf(acc[mt][2][reg], acc[mt][3][reg]));
      mx = rowmax16(mx);
      float s = 0.f;
#pragma unroll
      for (int nt = 0; nt < 4; ++nt) {
        float pe = __expf((acc[mt][nt][reg] - mx) * SCALE);
        acc[mt][nt][reg] = pe;
        s += pe;
      }
      l[mt][reg] = rowsum16(s);
    }

  // --- P -> LDS (C-layout scatter, stride 72: 16B-aligned rows for b128 reads)
  bf16_t* P = Ps + wid * (64 * 72);
#pragma unroll
  for (int mt = 0; mt < 4; ++mt)
#pragma unroll
    for (int nt = 0; nt < 4; ++nt)
#pragma unroll
      for (int reg = 0; reg < 4; ++reg)
        P[(mt * 16 + quad * 4 + reg) * 72 + nt * 16 + lc] = (bf16_t)acc[mt][nt][reg];

  // --- O = P.V  (A-frag = P rows from LDS; B-frag = vf)
  f32x4 oacc[4][2] = {};
#pragma unroll
  for (int mt = 0; mt < 4; ++mt) {
    bf16x8 pf0 = *(const bf16x8*)(P + (mt * 16 + lc) * 72 + quad * 8);
    bf16x8 pf1 = *(const bf16x8*)(P + (mt * 16 + lc) * 72 + 32 + quad * 8);
#pragma unroll
    for (int dt = 0; dt < 2; ++dt) {
      oacc[mt][dt] = __builtin_amdgcn_mfma_f32_16x16x32_bf16(pf0, vf[0][dt], oacc[mt][dt], 0, 0, 0);
      oacc[mt][dt] = __builtin_amdgcn_mfma_f32_16x16x32_bf16(pf1, vf[1][dt], oacc[mt][dt], 0, 0, 0);
    }
  }

  // --- write O into q slot (rows m<49), folding 1/l
#pragma unroll
  for (int mt = 0; mt < 4; ++mt)
#pragma unroll
    for (int reg = 0; reg < 4; ++reg) {
      int m = mt * 16 + quad * 4 + reg;
      if (m < 49) {
        float rl = __builtin_amdgcn_rcpf(l[mt][reg]);
        bf16_t* r = qkv + rowoff(m);
        r[lc]      = (bf16_t)(oacc[mt][0][reg] * rl);
        r[16 + lc] = (bf16_t)(oacc[mt][1][reg] * rl);
      }
    }
}

// ---------------------------------------------------------------------------
extern "C" void kernel_launch(void* const* d_in, const int* in_sizes, int n_in,
                              void* d_out, int out_size, void* d_ws, size_t ws_size,
                              hipStream_t stream) {
  const float* x      = (const float*)d_in[0];
  const float* w_qkv  = (const float*)d_in[1];
  const float* pos    = (const float*)d_in[2];
  const float* w_out  = (const float*)d_in[3];
  const float* b_out  = (const float*)d_in[4];
  const float* w_post = (const float*)d_in[5];
  const float* b_post = (const float*)d_in[6];
  float* out = (float*)d_out;

  const size_t SZ_QKV  = (size_t)M_TOT * 1152 * 2;   // 115.6 MB
  const size_t SZ_WT   = (size_t)1152 * 384 * 2;
  const size_t SZ_WC   = (size_t)384 * 384 * 2;
  const size_t SZ_BC   = 384 * 4;
  const size_t SZ_BIAS = (size_t)4 * 16 * 64 * 4 * 4;  // 64 KB
  const size_t NEEDED  = SZ_QKV + SZ_WT + SZ_WC + SZ_BC + SZ_BIAS;

  if (ws_size < NEEDED) {
    k_zero<<<(out_size + 255) / 256, 256, 0, stream>>>(out, out_size);
    return;
  }

  char* ws = (char*)d_ws;
  bf16_t* qkv   = (bf16_t*)ws;
  bf16_t* wT    = (bf16_t*)(ws + SZ_QKV);
  bf16_t* wcT   = (bf16_t*)(ws + SZ_QKV + SZ_WT);
  float*  bc    = (float*)(ws + SZ_QKV + SZ_WT + SZ_WC);
  float*  biasC = (float*)(ws + SZ_QKV + SZ_WT + SZ_WC + SZ_BC);
  bf16_t* xb    = (bf16_t*)d_out;   // d_out as scratch; dead before final GEMM

  k_transpose<<<1728, 256, 0, stream>>>(w_qkv, wT);
  k_comb<<<384, 256, 0, stream>>>(w_out, b_out, w_post, b_post, wcT, bc);
  k_bias<<<64, 256, 0, stream>>>(pos, biasC);
  k_convroll<<<(M_TOT * 96 + 255) / 256, 256, 0, stream>>>(x, xb);
  // qkv = xb @ w_qkv^T-laid-out   [50176 x 1152] bf16
  k_gemm<0><<<dim3(9, 392), 256, 0, stream>>>(xb, wT, qkv, nullptr, 1152, DIMK, DIMK);
  // attention in place (q slot)
  k_attn<<<3072, 256, 0, stream>>>(biasC, qkv);
  // out = roll^{-1}( attn @ wcomb + bcomb )   [50176 x 384] fp32
  k_gemm<1><<<dim3(3, 392), 256, 0, stream>>>(qkv, wcT, out, bc, 384, DIMK, 1152);
}